// Round 1
// baseline (151.891 us; speedup 1.0000x reference)
//
#include <hip/hip_runtime.h>
#include <math.h>

#define NTOK 16384   // B*S = 4*4096
#define DDIM 2048
#define NEXP 64
#define TOKB 64      // tokens per router block

// ws layout (floats): [0:64) cnt, [64:128) Psum, [128] zsum, [256 : 256+2048*64) wT

__global__ void k_transpose(const float* __restrict__ gw, float* __restrict__ wT) {
    int idx = blockIdx.x * 256 + threadIdx.x;   // 131072 total
    int k = idx >> 6, e = idx & 63;
    wT[idx] = gw[e * DDIM + k];                 // wT[k][e] = gw[e][k]
}

__global__ __launch_bounds__(512, 2)
void k_router(const float* __restrict__ x, const float* __restrict__ wT,
              float* __restrict__ out, float* __restrict__ gcnt,
              float* __restrict__ gP, float* __restrict__ gz) {
    __shared__ float Xs[TOKB][65];       // stride 65: (lane + c) % 32 -> 2-way, free
    __shared__ float Lg[2][TOKB][65];    // logit partials per k-half
    __shared__ float Ps[NEXP];
    __shared__ float Cnt[NEXP];
    __shared__ float Zs;

    const int tid = threadIdx.x;
    if (tid < NEXP) { Ps[tid] = 0.f; Cnt[tid] = 0.f; }
    if (tid == 0) Zs = 0.f;

    const int tok0 = blockIdx.x * TOKB;
    const int lane = tid & 63;
    // wave id: 8 waves = 4 expert-groups x 2 k-halves. Force wave-uniform so the
    // compiler emits s_load for the W reads (SGPR-broadcast FMA operand).
    const int wvu = __builtin_amdgcn_readfirstlane(tid >> 6);
    const int g16 = (wvu & 3) << 4;   // expert group base (0,16,32,48)
    const int khu = wvu >> 2;         // k-half (0 or 1)

    // staging map: 512 threads stage Xs[64][64] = 64 tokens x (32 k's per half)
    const int sr  = tid >> 3;         // token row 0..63
    const int scq = (tid & 7) << 3;   // col 0..56 step 8
    const int skk = (scq < 32) ? scq : (1024 + scq - 32);
    const float* srcbase = x + (size_t)(tok0 + sr) * DDIM + skk;

    float accA[16], accB[16];
    #pragma unroll
    for (int j = 0; j < 16; ++j) { accA[j] = 0.f; accB[j] = 0.f; }

    const float* __restrict__ wB0 = wT + (((size_t)khu * 1024) << 6) + g16;

    for (int k0 = 0; k0 < 1024; k0 += 32) {
        // ---- stage 32 k's per half into LDS (coalesced float4 global loads)
        float4 a = *(const float4*)(srcbase + k0);
        float4 b = *(const float4*)(srcbase + k0 + 4);
        float* dst = &Xs[sr][scq];
        dst[0]=a.x; dst[1]=a.y; dst[2]=a.z; dst[3]=a.w;
        dst[4]=b.x; dst[5]=b.y; dst[6]=b.z; dst[7]=b.w;
        __syncthreads();

        const float* xr = &Xs[lane][khu * 32];
        const float* wb = wB0 + ((size_t)k0 << 6);
        #pragma unroll 4
        for (int kk = 0; kk < 32; kk += 2) {
            float xk0 = xr[kk];
            float xk1 = xr[kk + 1];
            const float* w0 = wb + ((size_t)kk << 6);
            const float* w1 = w0 + 64;
            #pragma unroll
            for (int j = 0; j < 16; ++j) accA[j] = fmaf(w0[j], xk0, accA[j]);
            #pragma unroll
            for (int j = 0; j < 16; ++j) accB[j] = fmaf(w1[j], xk1, accB[j]);
        }
        __syncthreads();
    }

    // ---- write logit partials (this wave: 64 tokens x 16 experts x 1 k-half)
    #pragma unroll
    for (int j = 0; j < 16; ++j)
        Lg[khu][lane][g16 + j] = accA[j] + accB[j];
    __syncthreads();

    // ---- phase 2: per-token softmax / top-2 / aux.  lane = expert.
    float Pacc = 0.f;
    float zacc = 0.f;
    const int wv = tid >> 6;
    for (int t = wv * 8; t < wv * 8 + 8; ++t) {
        float l = Lg[0][t][lane] + Lg[1][t][lane];
        float m = l;
        #pragma unroll
        for (int off = 32; off > 0; off >>= 1) m = fmaxf(m, __shfl_xor(m, off));
        float s = expf(l - m);
        float sum = s;
        #pragma unroll
        for (int off = 32; off > 0; off >>= 1) sum += __shfl_xor(sum, off);
        Pacc += s / sum;                       // softmax weight of expert 'lane'

        unsigned long long b1 = __ballot(l == m);
        int i1 = __ffsll(b1) - 1;              // lowest index on ties (lax.top_k)
        float l2 = (lane == i1) ? -INFINITY : l;
        float m2 = l2;
        #pragma unroll
        for (int off = 32; off > 0; off >>= 1) m2 = fmaxf(m2, __shfl_xor(m2, off));
        unsigned long long b2 = __ballot(l2 == m2);
        int i2 = __ffsll(b2) - 1;

        if (lane == 0) {
            float s2  = expf(m2 - m);          // exp weight of 2nd vs 1st (=1)
            float inv = 1.f / (1.f + s2);
            int gt = tok0 + t;
            ((float2*)out)[gt]              = make_float2((float)i1, (float)i2);
            ((float2*)(out + 2 * NTOK))[gt] = make_float2(inv, s2 * inv);
            atomicAdd(&Cnt[i1], 1.f);
            atomicAdd(&Cnt[i2], 1.f);
            float lse = m + logf(sum);
            zacc += lse * lse;
        }
    }
    atomicAdd(&Ps[lane], Pacc);
    if (lane == 0) atomicAdd(&Zs, zacc);
    __syncthreads();

    if (tid < NEXP) {
        atomicAdd(&gcnt[tid], Cnt[tid]);
        atomicAdd(&gP[tid],   Ps[tid]);
    }
    if (tid == 0) atomicAdd(gz, Zs);
}

__global__ void k_final(const float* __restrict__ ws, float* __restrict__ out) {
    int lane = threadIdx.x;  // 64 threads, 1 wave
    float v = ws[lane] * ws[64 + lane];   // cnt_e * Psum_e
    #pragma unroll
    for (int off = 32; off > 0; off >>= 1) v += __shfl_xor(v, off);
    if (lane == 0) {
        // balance = E * sum( (cnt/(B*S*K)) * (Psum/(B*S)) )
        float bal = 64.f * v / (32768.f * 16384.f);
        float z   = ws[128] / 16384.f;
        out[4 * NTOK] = 0.01f * bal + 0.001f * z;   // out[65536]
    }
}

extern "C" void kernel_launch(void* const* d_in, const int* in_sizes, int n_in,
                              void* d_out, int out_size, void* d_ws, size_t ws_size,
                              hipStream_t stream) {
    const float* x  = (const float*)d_in[0];
    const float* gw = (const float*)d_in[1];
    float* out = (float*)d_out;
    float* wsf = (float*)d_ws;

    // zero the 129-float accumulator region every call (replay-safe)
    hipMemsetAsync(d_ws, 0, 516, stream);

    float* wT = wsf + 256;
    k_transpose<<<DDIM * NEXP / 256, 256, 0, stream>>>(gw, wT);
    k_router<<<NTOK / TOKB, 512, 0, stream>>>(x, wT, out, wsf, wsf + 64, wsf + 128);
    k_final<<<1, 64, 0, stream>>>(wsf, out);
}

// Round 2
// 85.038 us; speedup vs baseline: 1.7862x; 1.7862x over previous
//
#include <hip/hip_runtime.h>
#include <math.h>

#define NTOK 16384   // B*S
#define DDIM 2048
#define NEXP 64
#define MTILE 32     // tokens per block
#define KSUP 128     // k per LDS superstep
#define NSUP 16      // DDIM / KSUP

typedef __attribute__((ext_vector_type(8))) short bf16x8;
typedef __attribute__((ext_vector_type(4))) float f32x4;

// ---- 3-way bf16 split: x ~= h + m + l, residual <= 2^-27 |x| ----
__device__ __forceinline__ unsigned short f2bf(float f) {
    unsigned int u = __builtin_bit_cast(unsigned int, f);
    u += 0x7fffu + ((u >> 16) & 1u);          // RNE to bf16
    return (unsigned short)(u >> 16);
}
__device__ __forceinline__ float bf2f(unsigned short s) {
    return __builtin_bit_cast(float, ((unsigned int)s) << 16);
}
__device__ __forceinline__ void split3(float x, unsigned short &h,
                                       unsigned short &m, unsigned short &l) {
    h = f2bf(x);
    float r1 = x - bf2f(h);    // exact (Sterbenz)
    m = f2bf(r1);
    float r2 = r1 - bf2f(m);   // exact
    l = f2bf(r2);
}

// ---- pack gate_w into B-fragment layout: wp[(eg*64+ks)*3 + p][lane][8 bf16] ----
__global__ void k_wpack(const float* __restrict__ gw, unsigned short* __restrict__ wp) {
    int idx = blockIdx.x * 256 + threadIdx.x;   // 16384 threads
    int lane = idx & 63;
    int ks   = (idx >> 6) & 63;                 // global k-step (32 k each)
    int eg   = idx >> 12;                       // expert group 0..3
    int e  = eg * 16 + (lane & 15);
    int k0 = ks * 32 + (lane >> 4) * 8;
    const float* src = gw + (size_t)e * DDIM + k0;
    union { unsigned short s[8]; uint4 v; } H, M, L;
    #pragma unroll
    for (int j = 0; j < 8; ++j) split3(src[j], H.s[j], M.s[j], L.s[j]);
    size_t fb = (size_t)(eg * 64 + ks) * 3 * 512 + lane * 8;   // shorts
    *(uint4*)(wp + fb)        = H.v;
    *(uint4*)(wp + fb + 512)  = M.v;
    *(uint4*)(wp + fb + 1024) = L.v;
}

// ---- main: GEMM (6-pass split-bf16 MFMA) + softmax + top2 + aux, fused ----
__global__ __launch_bounds__(256, 2)
void k_main(const float* __restrict__ x, const unsigned short* __restrict__ wp,
            float* __restrict__ out, float* __restrict__ gcnt,
            float* __restrict__ gP, float* __restrict__ gz) {
    // As: [2 buf][3 part][32 tok][128 k] bf16, 16B slots XOR-swizzled by (tok&15)
    __shared__ __align__(16) char As[2 * 3 * MTILE * KSUP * 2];   // 48 KB
    __shared__ float Lg[MTILE][65];
    __shared__ float Ps[NEXP], Cnt[NEXP], Zs;

    const int tid = threadIdx.x;
    if (tid < NEXP) { Ps[tid] = 0.f; Cnt[tid] = 0.f; }
    if (tid == 0) Zs = 0.f;

    const int tok0 = blockIdx.x * MTILE;
    const int lane = tid & 63;
    const int eg   = __builtin_amdgcn_readfirstlane(tid >> 6);   // wave = expert group

    // staging map: thread loads 4 consecutive floats for rows tokq+8r, r=0..3
    const int subk = tid & 31;
    const int tokq = tid >> 5;   // 0..7
    const float* xbase = x + (size_t)(tok0 + tokq) * DDIM + subk * 4;

    float4 cur0 = *(const float4*)(xbase);
    float4 cur1 = *(const float4*)(xbase + 8 * DDIM);
    float4 cur2 = *(const float4*)(xbase + 16 * DDIM);
    float4 cur3 = *(const float4*)(xbase + 24 * DDIM);

    f32x4 acc0 = {0.f, 0.f, 0.f, 0.f};
    f32x4 acc1 = {0.f, 0.f, 0.f, 0.f};

    const int tau   = lane & 15;
    const int kappa = lane >> 4;

    for (int ss = 0; ss < NSUP; ++ss) {
        char* bb = As + (ss & 1) * 24576;
        // ---- convert + write current superstep into LDS buf ----
        {
            float4 v[4] = {cur0, cur1, cur2, cur3};
            #pragma unroll
            for (int r = 0; r < 4; ++r) {
                int row = tokq + 8 * r;
                unsigned short h0,h1,h2,h3, m0,m1,m2,m3, l0,l1,l2,l3;
                split3(v[r].x, h0, m0, l0);
                split3(v[r].y, h1, m1, l1);
                split3(v[r].z, h2, m2, l2);
                split3(v[r].w, h3, m3, l3);
                uint2 H = make_uint2((unsigned)h0 | ((unsigned)h1 << 16),
                                     (unsigned)h2 | ((unsigned)h3 << 16));
                uint2 M = make_uint2((unsigned)m0 | ((unsigned)m1 << 16),
                                     (unsigned)m2 | ((unsigned)m3 << 16));
                uint2 L = make_uint2((unsigned)l0 | ((unsigned)l1 << 16),
                                     (unsigned)l2 | ((unsigned)l3 << 16));
                char* pb = bb + row * 256 + (((subk >> 1) ^ (row & 15)) << 4)
                              + (subk & 1) * 8;
                *(uint2*)(pb)         = H;    // part 0
                *(uint2*)(pb + 8192)  = M;    // part 1
                *(uint2*)(pb + 16384) = L;    // part 2
            }
        }
        // ---- prefetch next superstep ----
        if (ss + 1 < NSUP) {
            const float* nb = xbase + (ss + 1) * KSUP;
            cur0 = *(const float4*)(nb);
            cur1 = *(const float4*)(nb + 8 * DDIM);
            cur2 = *(const float4*)(nb + 16 * DDIM);
            cur3 = *(const float4*)(nb + 24 * DDIM);
        }
        __syncthreads();
        // ---- 4 MFMA k-steps on this buffer ----
        #pragma unroll
        for (int ks = 0; ks < 4; ++ks) {
            int ksg = ss * 4 + ks;
            const unsigned short* f = wp + (size_t)(eg * 64 + ksg) * 3 * 512 + lane * 8;
            bf16x8 Bh = *(const bf16x8*)(f);
            bf16x8 Bm = *(const bf16x8*)(f + 512);
            bf16x8 Bl = *(const bf16x8*)(f + 1024);

            int slotr = ((ks * 4 + kappa) ^ tau) << 4;
            const char* p0 = bb + tau * 256 + slotr;          // tg=0
            const char* p1 = bb + (16 + tau) * 256 + slotr;   // tg=1
            bf16x8 Ah0 = *(const bf16x8*)(p0);
            bf16x8 Am0 = *(const bf16x8*)(p0 + 8192);
            bf16x8 Al0 = *(const bf16x8*)(p0 + 16384);
            bf16x8 Ah1 = *(const bf16x8*)(p1);
            bf16x8 Am1 = *(const bf16x8*)(p1 + 8192);
            bf16x8 Al1 = *(const bf16x8*)(p1 + 16384);

            acc0 = __builtin_amdgcn_mfma_f32_16x16x32_bf16(Ah0, Bh, acc0, 0, 0, 0);
            acc0 = __builtin_amdgcn_mfma_f32_16x16x32_bf16(Ah0, Bm, acc0, 0, 0, 0);
            acc0 = __builtin_amdgcn_mfma_f32_16x16x32_bf16(Am0, Bh, acc0, 0, 0, 0);
            acc0 = __builtin_amdgcn_mfma_f32_16x16x32_bf16(Ah0, Bl, acc0, 0, 0, 0);
            acc0 = __builtin_amdgcn_mfma_f32_16x16x32_bf16(Al0, Bh, acc0, 0, 0, 0);
            acc0 = __builtin_amdgcn_mfma_f32_16x16x32_bf16(Am0, Bm, acc0, 0, 0, 0);

            acc1 = __builtin_amdgcn_mfma_f32_16x16x32_bf16(Ah1, Bh, acc1, 0, 0, 0);
            acc1 = __builtin_amdgcn_mfma_f32_16x16x32_bf16(Ah1, Bm, acc1, 0, 0, 0);
            acc1 = __builtin_amdgcn_mfma_f32_16x16x32_bf16(Am1, Bh, acc1, 0, 0, 0);
            acc1 = __builtin_amdgcn_mfma_f32_16x16x32_bf16(Ah1, Bl, acc1, 0, 0, 0);
            acc1 = __builtin_amdgcn_mfma_f32_16x16x32_bf16(Al1, Bh, acc1, 0, 0, 0);
            acc1 = __builtin_amdgcn_mfma_f32_16x16x32_bf16(Am1, Bm, acc1, 0, 0, 0);
        }
        __syncthreads();
    }

    // ---- logits to LDS: C/D layout col=lane&15 (expert), row=(lane>>4)*4+j (token)
    #pragma unroll
    for (int j = 0; j < 4; ++j) {
        Lg[kappa * 4 + j][eg * 16 + tau]      = acc0[j];
        Lg[16 + kappa * 4 + j][eg * 16 + tau] = acc1[j];
    }
    __syncthreads();

    // ---- phase 2: softmax / top-2 / aux. lane = expert, each wave 8 tokens.
    float Pacc = 0.f, zacc = 0.f;
    const int wv = tid >> 6;
    for (int i = 0; i < 8; ++i) {
        int t = wv * 8 + i;
        float l = Lg[t][lane];
        float mx = l;
        #pragma unroll
        for (int off = 32; off > 0; off >>= 1) mx = fmaxf(mx, __shfl_xor(mx, off));
        float s = expf(l - mx);
        float sum = s;
        #pragma unroll
        for (int off = 32; off > 0; off >>= 1) sum += __shfl_xor(sum, off);
        Pacc += s / sum;

        unsigned long long b1 = __ballot(l == mx);
        int i1 = __ffsll(b1) - 1;              // lowest index on ties
        float l2 = (lane == i1) ? -INFINITY : l;
        float m2 = l2;
        #pragma unroll
        for (int off = 32; off > 0; off >>= 1) m2 = fmaxf(m2, __shfl_xor(m2, off));
        unsigned long long b2 = __ballot(l2 == m2);
        int i2 = __ffsll(b2) - 1;

        if (lane == 0) {
            float s2  = expf(m2 - mx);
            float inv = 1.f / (1.f + s2);
            int gt = tok0 + t;
            ((float2*)out)[gt]              = make_float2((float)i1, (float)i2);
            ((float2*)(out + 2 * NTOK))[gt] = make_float2(inv, s2 * inv);
            atomicAdd(&Cnt[i1], 1.f);
            atomicAdd(&Cnt[i2], 1.f);
            float lse = mx + logf(sum);
            zacc += lse * lse;
        }
    }
    atomicAdd(&Ps[lane], Pacc);
    if (lane == 0) atomicAdd(&Zs, zacc);
    __syncthreads();

    if (tid < NEXP) {
        atomicAdd(&gcnt[tid], Cnt[tid]);
        atomicAdd(&gP[tid],   Ps[tid]);
    }
    if (tid == 0) atomicAdd(gz, Zs);
}

__global__ void k_final(const float* __restrict__ ws, float* __restrict__ out) {
    int lane = threadIdx.x;  // 64 threads
    float v = ws[lane] * ws[64 + lane];   // cnt_e * Psum_e
    #pragma unroll
    for (int off = 32; off > 0; off >>= 1) v += __shfl_xor(v, off);
    if (lane == 0) {
        float bal = 64.f * v / (32768.f * 16384.f);
        float z   = ws[128] / 16384.f;
        out[4 * NTOK] = 0.01f * bal + 0.001f * z;
    }
}

extern "C" void kernel_launch(void* const* d_in, const int* in_sizes, int n_in,
                              void* d_out, int out_size, void* d_ws, size_t ws_size,
                              hipStream_t stream) {
    const float* x  = (const float*)d_in[0];
    const float* gw = (const float*)d_in[1];
    float* out = (float*)d_out;
    float* wsf = (float*)d_ws;
    unsigned short* wp = (unsigned short*)((char*)d_ws + 1024);

    hipMemsetAsync(d_ws, 0, 516, stream);   // zero aux accumulators
    k_wpack<<<64, 256, 0, stream>>>(gw, wp);
    k_main<<<NTOK / MTILE, 256, 0, stream>>>(x, wp, out, wsf, wsf + 64, wsf + 128);
    k_final<<<1, 64, 0, stream>>>(wsf, out);
}

// Round 4
// 84.222 us; speedup vs baseline: 1.8035x; 1.0097x over previous
//
#include <hip/hip_runtime.h>
#include <math.h>

#define NTOK 16384   // B*S
#define DDIM 2048
#define NEXP 64
#define MTILE 32     // tokens per block
#define KSUP 128     // k per LDS superstep
#define NSUP 16      // DDIM / KSUP

typedef __attribute__((ext_vector_type(8))) short bf16x8;
typedef __attribute__((ext_vector_type(4))) float f32x4;

// ---- 3-way bf16 split: x ~= h + m + l, residual <= 2^-27 |x| ----
__device__ __forceinline__ unsigned short f2bf(float f) {
    unsigned int u = __builtin_bit_cast(unsigned int, f);
    u += 0x7fffu + ((u >> 16) & 1u);          // RNE to bf16
    return (unsigned short)(u >> 16);
}
__device__ __forceinline__ float bf2f(unsigned short s) {
    return __builtin_bit_cast(float, ((unsigned int)s) << 16);
}
__device__ __forceinline__ void split3(float x, unsigned short &h,
                                       unsigned short &m, unsigned short &l) {
    h = f2bf(x);
    float r1 = x - bf2f(h);    // exact (Sterbenz)
    m = f2bf(r1);
    float r2 = r1 - bf2f(m);   // exact
    l = f2bf(r2);
}

// ---- pack gate_w into B-fragment layout: wp[(eg*64+ks)*3*512 + p*512 + lane*8]
__global__ void k_wpack(const float* __restrict__ gw, unsigned short* __restrict__ wp) {
    int idx = blockIdx.x * 256 + threadIdx.x;   // 16384 threads
    int lane = idx & 63;
    int ks   = (idx >> 6) & 63;                 // global k-step (32 k each)
    int eg   = idx >> 12;                       // expert group 0..3
    int e  = eg * 16 + (lane & 15);
    int k0 = ks * 32 + (lane >> 4) * 8;
    const float* src = gw + (size_t)e * DDIM + k0;
    union { unsigned short s[8]; uint4 v; } H, M, L;
    #pragma unroll
    for (int j = 0; j < 8; ++j) split3(src[j], H.s[j], M.s[j], L.s[j]);
    size_t fb = (size_t)(eg * 64 + ks) * 1536 + lane * 8;   // shorts
    *(uint4*)(wp + fb)        = H.v;
    *(uint4*)(wp + fb + 512)  = M.v;
    *(uint4*)(wp + fb + 1024) = L.v;
}

// ---- main: GEMM (6-pass split-bf16 MFMA) + softmax + top2 + aux, fused ----
__global__ __launch_bounds__(256, 4)
void k_main(const float* __restrict__ x, const unsigned short* __restrict__ wp,
            float* __restrict__ out, float* __restrict__ gcnt,
            float* __restrict__ gP, float* __restrict__ gz) {
    // As: [3 part][32 tok][128 k] bf16, 16B slots XOR-swizzled by (tok&15).
    // Single-buffered: stage -> barrier -> read -> barrier makes dbuf redundant.
    __shared__ __align__(16) char As[24576];
    __shared__ float Lg[MTILE][65];
    __shared__ float Ps[NEXP], Cnt[NEXP], Zs;

    const int tid = threadIdx.x;
    if (tid < NEXP) { Ps[tid] = 0.f; Cnt[tid] = 0.f; }
    if (tid == 0) Zs = 0.f;

    const int tok0 = blockIdx.x * MTILE;
    const int lane = tid & 63;
    const int eg   = __builtin_amdgcn_readfirstlane(tid >> 6);   // wave = expert group

    // staging map: thread loads 4 consecutive floats for rows tokq+8r, r=0..3
    const int subk = tid & 31;
    const int tokq = tid >> 5;   // 0..7
    const float* xbase = x + (size_t)(tok0 + tokq) * DDIM + subk * 4;

    float4 cur0 = *(const float4*)(xbase);
    float4 cur1 = *(const float4*)(xbase + 8 * DDIM);
    float4 cur2 = *(const float4*)(xbase + 16 * DDIM);
    float4 cur3 = *(const float4*)(xbase + 24 * DDIM);

    f32x4 acc0 = {0.f, 0.f, 0.f, 0.f};
    f32x4 acc1 = {0.f, 0.f, 0.f, 0.f};

    const int tau   = lane & 15;
    const int kappa = lane >> 4;

    // W fragment rolling register prefetch, 2 ksteps deep (wf[ks&1])
    const unsigned short* wpe = wp + (size_t)eg * 64 * 1536 + lane * 8;
    bf16x8 wf[2][3];
    #pragma unroll
    for (int p = 0; p < 3; ++p) wf[0][p] = *(const bf16x8*)(wpe + p * 512);
    #pragma unroll
    for (int p = 0; p < 3; ++p) wf[1][p] = *(const bf16x8*)(wpe + 1536 + p * 512);

    for (int ss = 0; ss < NSUP; ++ss) {
        char* bb = As;
        // ---- convert + write current superstep into LDS ----
        {
            float4 v[4] = {cur0, cur1, cur2, cur3};
            #pragma unroll
            for (int r = 0; r < 4; ++r) {
                int row = tokq + 8 * r;
                unsigned short h0,h1,h2,h3, m0,m1,m2,m3, l0,l1,l2,l3;
                split3(v[r].x, h0, m0, l0);
                split3(v[r].y, h1, m1, l1);
                split3(v[r].z, h2, m2, l2);
                split3(v[r].w, h3, m3, l3);
                uint2 H = make_uint2((unsigned)h0 | ((unsigned)h1 << 16),
                                     (unsigned)h2 | ((unsigned)h3 << 16));
                uint2 M = make_uint2((unsigned)m0 | ((unsigned)m1 << 16),
                                     (unsigned)m2 | ((unsigned)m3 << 16));
                uint2 L = make_uint2((unsigned)l0 | ((unsigned)l1 << 16),
                                     (unsigned)l2 | ((unsigned)l3 << 16));
                char* pb = bb + row * 256 + (((subk >> 1) ^ (row & 15)) << 4)
                              + (subk & 1) * 8;
                *(uint2*)(pb)         = H;    // part 0
                *(uint2*)(pb + 8192)  = M;    // part 1
                *(uint2*)(pb + 16384) = L;    // part 2
            }
        }
        // ---- prefetch next superstep's x ----
        if (ss + 1 < NSUP) {
            const float* nb = xbase + (ss + 1) * KSUP;
            cur0 = *(const float4*)(nb);
            cur1 = *(const float4*)(nb + 8 * DDIM);
            cur2 = *(const float4*)(nb + 16 * DDIM);
            cur3 = *(const float4*)(nb + 24 * DDIM);
        }
        __syncthreads();
        // ---- 4 MFMA k-steps; W regs for kstep ks+2 loaded while ks computes
        #pragma unroll
        for (int ks = 0; ks < 4; ++ks) {
            int slotr = ((ks * 4 + kappa) ^ tau) << 4;
            const char* p0 = bb + tau * 256 + slotr;          // tokens 0..15
            const char* p1 = bb + (16 + tau) * 256 + slotr;   // tokens 16..31
            bf16x8 Ah0 = *(const bf16x8*)(p0);
            bf16x8 Am0 = *(const bf16x8*)(p0 + 8192);
            bf16x8 Al0 = *(const bf16x8*)(p0 + 16384);
            bf16x8 Ah1 = *(const bf16x8*)(p1);
            bf16x8 Am1 = *(const bf16x8*)(p1 + 8192);
            bf16x8 Al1 = *(const bf16x8*)(p1 + 16384);
            bf16x8 Bh = wf[ks & 1][0];
            bf16x8 Bm = wf[ks & 1][1];
            bf16x8 Bl = wf[ks & 1][2];

            acc0 = __builtin_amdgcn_mfma_f32_16x16x32_bf16(Ah0, Bh, acc0, 0, 0, 0);
            acc0 = __builtin_amdgcn_mfma_f32_16x16x32_bf16(Ah0, Bm, acc0, 0, 0, 0);
            acc0 = __builtin_amdgcn_mfma_f32_16x16x32_bf16(Am0, Bh, acc0, 0, 0, 0);
            acc0 = __builtin_amdgcn_mfma_f32_16x16x32_bf16(Ah0, Bl, acc0, 0, 0, 0);
            acc0 = __builtin_amdgcn_mfma_f32_16x16x32_bf16(Al0, Bh, acc0, 0, 0, 0);
            acc0 = __builtin_amdgcn_mfma_f32_16x16x32_bf16(Am0, Bm, acc0, 0, 0, 0);

            acc1 = __builtin_amdgcn_mfma_f32_16x16x32_bf16(Ah1, Bh, acc1, 0, 0, 0);
            acc1 = __builtin_amdgcn_mfma_f32_16x16x32_bf16(Ah1, Bm, acc1, 0, 0, 0);
            acc1 = __builtin_amdgcn_mfma_f32_16x16x32_bf16(Am1, Bh, acc1, 0, 0, 0);
            acc1 = __builtin_amdgcn_mfma_f32_16x16x32_bf16(Ah1, Bl, acc1, 0, 0, 0);
            acc1 = __builtin_amdgcn_mfma_f32_16x16x32_bf16(Al1, Bh, acc1, 0, 0, 0);
            acc1 = __builtin_amdgcn_mfma_f32_16x16x32_bf16(Am1, Bm, acc1, 0, 0, 0);

            int nk = ((ss << 2) + ks + 2) & 63;   // wraps harmlessly on last ss
            #pragma unroll
            for (int pI = 0; pI < 3; ++pI)
                wf[ks & 1][pI] = *(const bf16x8*)(wpe + (size_t)nk * 1536 + pI * 512);
        }
        __syncthreads();
    }

    // ---- logits to LDS: C/D layout col=lane&15 (expert), row=(lane>>4)*4+j
    #pragma unroll
    for (int j = 0; j < 4; ++j) {
        Lg[kappa * 4 + j][eg * 16 + tau]      = acc0[j];
        Lg[16 + kappa * 4 + j][eg * 16 + tau] = acc1[j];
    }
    __syncthreads();

    // ---- phase 2: softmax / top-2 / aux. lane = expert, each wave 8 tokens.
    float Pacc = 0.f, zacc = 0.f;
    const int wv = tid >> 6;
    for (int i = 0; i < 8; ++i) {
        int t = wv * 8 + i;
        float l = Lg[t][lane];
        float mx = l;
        #pragma unroll
        for (int off = 32; off > 0; off >>= 1) mx = fmaxf(mx, __shfl_xor(mx, off));
        float s = expf(l - mx);
        float sum = s;
        #pragma unroll
        for (int off = 32; off > 0; off >>= 1) sum += __shfl_xor(sum, off);
        Pacc += s / sum;

        unsigned long long b1 = __ballot(l == mx);
        int i1 = __ffsll(b1) - 1;              // lowest index on ties
        float l2 = (lane == i1) ? -INFINITY : l;
        float m2 = l2;
        #pragma unroll
        for (int off = 32; off > 0; off >>= 1) m2 = fmaxf(m2, __shfl_xor(m2, off));
        unsigned long long b2 = __ballot(l2 == m2);
        int i2 = __ffsll(b2) - 1;

        if (lane == 0) {
            float s2  = expf(m2 - mx);
            float inv = 1.f / (1.f + s2);
            int gt = tok0 + t;
            ((float2*)out)[gt]              = make_float2((float)i1, (float)i2);
            ((float2*)(out + 2 * NTOK))[gt] = make_float2(inv, s2 * inv);
            atomicAdd(&Cnt[i1], 1.f);
            atomicAdd(&Cnt[i2], 1.f);
            float lse = mx + logf(sum);
            zacc += lse * lse;
        }
    }
    atomicAdd(&Ps[lane], Pacc);
    if (lane == 0) atomicAdd(&Zs, zacc);
    __syncthreads();

    if (tid < NEXP) {
        atomicAdd(&gcnt[tid], Cnt[tid]);
        atomicAdd(&gP[tid],   Ps[tid]);
    }
    if (tid == 0) atomicAdd(gz, Zs);
}

__global__ void k_final(const float* __restrict__ ws, float* __restrict__ out) {
    int lane = threadIdx.x;  // 64 threads
    float v = ws[lane] * ws[64 + lane];   // cnt_e * Psum_e
    #pragma unroll
    for (int off = 32; off > 0; off >>= 1) v += __shfl_xor(v, off);
    if (lane == 0) {
        float bal = 64.f * v / (32768.f * 16384.f);
        float z   = ws[128] / 16384.f;
        out[4 * NTOK] = 0.01f * bal + 0.001f * z;
    }
}

extern "C" void kernel_launch(void* const* d_in, const int* in_sizes, int n_in,
                              void* d_out, int out_size, void* d_ws, size_t ws_size,
                              hipStream_t stream) {
    const float* x  = (const float*)d_in[0];
    const float* gw = (const float*)d_in[1];
    float* out = (float*)d_out;
    float* wsf = (float*)d_ws;
    unsigned short* wp = (unsigned short*)((char*)d_ws + 1024);

    hipMemsetAsync(d_ws, 0, 516, stream);   // zero aux accumulators
    k_wpack<<<64, 256, 0, stream>>>(gw, wp);
    k_main<<<NTOK / MTILE, 256, 0, stream>>>(x, wp, out, wsf, wsf + 64, wsf + 128);
    k_final<<<1, 64, 0, stream>>>(wsf, out);
}